// Round 11
// baseline (16469.722 us; speedup 1.0000x reference)
//
#include <hip/hip_runtime.h>

#define Bdim 128
#define Tdim 256
#define Fdim 64
#define Hdim 1024
#define Pdim 512
#define OUTLEN 48

typedef float  f32x4 __attribute__((ext_vector_type(4)));
typedef short  s16x8 __attribute__((ext_vector_type(8)));
typedef unsigned short u16;

__device__ __forceinline__ u16 f2bf(float f) {
  unsigned u = __float_as_uint(f);
  u += 0x7FFFu + ((u >> 16) & 1u);   // RNE
  return (u16)(u >> 16);
}
__device__ __forceinline__ float bf2f(u16 s) { return __uint_as_float(((unsigned)s) << 16); }
// 16B-block XOR swizzle within a 128B row (G4 pattern); returns u16 offset of block
__device__ __forceinline__ int swz8(int row, int blk) { return ((blk ^ (row & 7)) << 3); }

__device__ __forceinline__ f32x4 mfma16(s16x8 a, s16x8 b, f32x4 c) {
  return __builtin_amdgcn_mfma_f32_16x16x32_bf16(a, b, c, 0, 0, 0);
}

// async global->LDS, 16B per lane; lds base must be wave-uniform (HW adds lane*16)
__device__ __forceinline__ void glds16(u16* lds, const u16* g) {
  __builtin_amdgcn_global_load_lds(
      (const __attribute__((address_space(1))) unsigned int*)g,
      (__attribute__((address_space(3))) unsigned int*)lds, 16, 0, 0);
}

// =====================================================================
// prep: fp32 weight [N][K] -> swizzled bf16 hi/lo plane tiles, 32-col blocks
// layout: [colblk][nc][2(hi,lo)][rows][64]  (rows = 96 gru / 32 lin)
// =====================================================================
__global__ __launch_bounds__(256)
void prep_w(const float* __restrict__ W, u16* __restrict__ dst,
            int colblks, int nc, int rows, int K, int gru) {
  int idx = blockIdx.x * 256 + threadIdx.x;
  if (idx >= colblks * nc * rows * 8) return;
  int blk = idx & 7;
  int t = idx >> 3;
  int r = t % rows; t /= rows;
  int c = t % nc;
  int cb = t / nc;
  int srow = gru ? ((r >> 5) * Hdim + cb * 32 + (r & 31)) : (cb * 32 + r);
  const float* src = W + (size_t)srow * K + c * 64 + blk * 8;
  s16x8 vh, vl;
#pragma unroll
  for (int e = 0; e < 8; ++e) {
    float v = src[e];
    u16 h = f2bf(v);
    vh[e] = (short)h;
    vl[e] = (short)f2bf(v - bf2f(h));
  }
  size_t tb = (size_t)(cb * nc + c) * (2 * rows * 64);
  int o = r * 64 + swz8(r, blk);
  *(s16x8*)(dst + tb + o) = vh;
  *(s16x8*)(dst + tb + (size_t)rows * 64 + o) = vl;
}

// X [128][256][64] fp32 -> per-t A-tiles [256][2][128][64]
__global__ __launch_bounds__(256)
void prep_x(const float* __restrict__ X, u16* __restrict__ dst) {
  int idx = blockIdx.x * 256 + threadIdx.x;   // 256*128*8
  int blk = idx & 7;
  int row = (idx >> 3) & 127;
  int t = idx >> 10;
  const float* src = X + (size_t)row * (Tdim * Fdim) + t * 64 + blk * 8;
  s16x8 vh, vl;
#pragma unroll
  for (int e = 0; e < 8; ++e) {
    float v = src[e];
    u16 h = f2bf(v);
    vh[e] = (short)h;
    vl[e] = (short)f2bf(v - bf2f(h));
  }
  size_t tb = (size_t)t * 16384;
  int o = row * 64 + swz8(row, blk);
  *(s16x8*)(dst + tb + o) = vh;
  *(s16x8*)(dst + tb + 8192 + o) = vl;
}

// =====================================================================
// one staged 64-k chunk (3-term hi/lo split), 64 rows x 32 cols per block:
// LDS buf: A hi[64][64] (4096 u16) | A lo (4096) | W hi[NG*32][64] | W lo
// each of 4 waves owns 16 A-rows; 2 column-subtiles (cg)
// =====================================================================
template<int NG, bool SEG1>
__device__ __forceinline__ void compute_chunk(const u16* __restrict__ A, int lane, int wv,
                                              f32x4 acc[][2]) {
  constexpr int WT = NG * 2048;            // u16 per W plane (NG*32 rows x 64)
  const u16* Wp = A + 8192;
#pragma unroll
  for (int kk = 0; kk < 2; ++kk) {
    const int sw = (((kk * 4 + (lane >> 4)) ^ (lane & 7)) << 3);
    const u16* ap = A + (wv * 16 + (lane & 15)) * 64 + sw;
    s16x8 ah = *(const s16x8*)(ap);
    s16x8 al = *(const s16x8*)(ap + 4096);
#pragma unroll
    for (int g = 0; g < NG; ++g) {
      const int q = (NG == 3 && g == 2) ? (SEG1 ? 3 : 2) : g;
#pragma unroll
      for (int cg = 0; cg < 2; ++cg) {
        const u16* wp = Wp + (g * 32 + cg * 16 + (lane & 15)) * 64 + sw;
        s16x8 bh = *(const s16x8*)(wp);
        s16x8 bl = *(const s16x8*)(wp + WT);
        acc[q][cg] = mfma16(ah, bh, acc[q][cg]);
        acc[q][cg] = mfma16(al, bh, acc[q][cg]);
        acc[q][cg] = mfma16(ah, bl, acc[q][cg]);
      }
    }
  }
}

// =====================================================================
// argument bundle for one GEMM instance (so two can share a launch)
// =====================================================================
struct GArgs {
  const u16* a0; const u16* w0; int nc0;
  const u16* a1; const u16* w1; int nc1;
  const float* bias0; const float* bias1;
  const u16* hprev; u16* oplanes; float* yout;
};

// =====================================================================
// GEMM body: full-K per block, 64 rows (rh) x 32 cols (cb), 3 LDS buffers,
// prefetch depth 2, direct register epilogue. No inter-block comms.
// NG=3 MODE=0: GRU (R,Z,IN,HN; epilogue -> h planes)
// NG=1 MODE=1: proj+relu -> p planes; MODE=2: out -> y planes + f32 d_out
// =====================================================================
template<int NG, int MODE>
__device__ __forceinline__ void gemm_body(u16* __restrict__ sm, const GArgs& g,
                                          int cb, int rh) {
  constexpr int WT = NG * 2048;            // u16 per W plane tile
  constexpr int BUFU = 8192 + 2 * WT;      // A(hi+lo, 64 rows) + W(hi+lo)
  constexpr int NQ = (NG == 3) ? 4 : 1;
  constexpr int D = 2;                     // prefetch depth (3 buffers)

  const int tid = threadIdx.x;
  const int lane = tid & 63;
  const int wv = tid >> 6;
  const int nc0 = g.nc0;
  const int NC = nc0 + g.nc1;

  f32x4 acc[NQ][2];
#pragma unroll
  for (int q = 0; q < NQ; ++q) {
    acc[q][0] = f32x4{0.f, 0.f, 0.f, 0.f};
    acc[q][1] = f32x4{0.f, 0.f, 0.f, 0.f};
  }

  auto stage = [&](int c, int buf) {
    const u16 *at, *wt;
    if (c < nc0) { at = g.a0 + (size_t)c * 16384; wt = g.w0 + (size_t)(cb * nc0 + c) * (2 * WT); }
    else { int cc = c - nc0; at = g.a1 + (size_t)cc * 16384; wt = g.w1 + (size_t)(cb * g.nc1 + cc) * (2 * WT); }
    u16* sa = sm + buf * BUFU;
    for (int i = wv; i < 16; i += 4)                 // A half: 16 KB -> 4 issues/wave
      glds16(sa + i * 512, at + ((i & 8) ? 8192 : 0) + rh * 4096 + (i & 7) * 512 + lane * 8);
    u16* swl = sa + 8192;
    // W tile is 2*WT u16 (hi+lo) = (WT>>8) segments of 512 u16.
    // r10 bug: used (WT>>9) here -> lo plane never staged -> NaN.
    for (int i = wv; i < (WT >> 8); i += 4)          // W: GRU 6/wave, LIN 2/wave
      glds16(swl + i * 512, wt + i * 512 + lane * 8);
  };
  // per-wave issues per stage: 4 + (WT>>8)/4 -> 10 (GRU) / 6 (linear)

  for (int p = 0; p < D && p < NC; ++p) stage(p, p % 3);
  for (int c = 0; c < NC; ++c) {
    if (c + D < NC) stage(c + D, (c + D) % 3);
    const int rem = NC - 1 - c;
    const int gg = rem < D ? rem : D;                // stage-groups newer than c
    if constexpr (NG == 3) {
      switch (gg) {
        case 2:  asm volatile("s_waitcnt vmcnt(20)" ::: "memory"); break;
        case 1:  asm volatile("s_waitcnt vmcnt(10)" ::: "memory"); break;
        default: asm volatile("s_waitcnt vmcnt(0)"  ::: "memory");
      }
    } else {
      switch (gg) {
        case 2:  asm volatile("s_waitcnt vmcnt(12)" ::: "memory"); break;
        case 1:  asm volatile("s_waitcnt vmcnt(6)"  ::: "memory"); break;
        default: asm volatile("s_waitcnt vmcnt(0)"  ::: "memory");
      }
    }
    __builtin_amdgcn_s_barrier();
    asm volatile("" ::: "memory");
    const u16* A = sm + (c % 3) * BUFU;
    if (c < nc0) compute_chunk<NG, false>(A, lane, wv, acc);
    else         compute_chunk<NG, true>(A, lane, wv, acc);
    asm volatile("s_waitcnt lgkmcnt(0)" ::: "memory");
    __builtin_amdgcn_s_barrier();
    asm volatile("" ::: "memory");
  }

  // ---- epilogue (C layout: col=lane&15, row(local)=wv*16+(lane>>4)*4+e) ----
  const int rowbase = rh * 64 + wv * 16 + ((lane >> 4) << 2);

#pragma unroll
  for (int cg = 0; cg < 2; ++cg) {
    const int j = cb * 32 + cg * 16 + (lane & 15);
    const int ch = j >> 6, k6 = j & 63;

    if constexpr (MODE == 0) {
      const float b_r = g.bias0[j] + g.bias1[j];
      const float b_z = g.bias0[Hdim + j] + g.bias1[Hdim + j];
      const float b_in = g.bias0[2 * Hdim + j];
      const float b_hn = g.bias1[2 * Hdim + j];
#pragma unroll
      for (int e = 0; e < 4; ++e) {
        const int r = rowbase + e;
        const int o = ch * 16384 + r * 64 + swz8(r, k6 >> 3) + (k6 & 7);
        const float hp = bf2f(g.hprev[o]) + bf2f(g.hprev[o + 8192]);
        const float rr = 1.f / (1.f + expf(-(acc[0][cg][e] + b_r)));
        const float zz = 1.f / (1.f + expf(-(acc[1][cg][e] + b_z)));
        const float nn = tanhf(acc[2][cg][e] + b_in + rr * (acc[3][cg][e] + b_hn));
        const float h = (1.f - zz) * nn + zz * hp;
        const u16 hh = f2bf(h);
        g.oplanes[o] = hh;
        g.oplanes[o + 8192] = f2bf(h - bf2f(hh));
      }
    } else {
      const float bb = g.bias0[j];
#pragma unroll
      for (int e = 0; e < 4; ++e) {
        const int r = rowbase + e;
        float v = acc[0][cg][e] + bb;
        if constexpr (MODE == 1) v = fmaxf(v, 0.f);
        const int o = ch * 16384 + r * 64 + swz8(r, k6 >> 3) + (k6 & 7);
        const u16 hh = f2bf(v);
        g.oplanes[o] = hh;
        g.oplanes[o + 8192] = f2bf(v - bf2f(hh));
        if constexpr (MODE == 2) g.yout[(size_t)r * (OUTLEN * Fdim) + j] = v;
      }
    }
  }
}

// flat-grid mapping: rh lives in bit 3 so (cb,rh=0) and (cb,rh=1) differ by 8
// -> same XCD under round-robin dispatch -> rh-duplicated W reads hit L2.
__device__ __forceinline__ void map_flat(int b, int& cb, int& rh) {
  rh = (b >> 3) & 1;
  cb = (b & 7) | ((b >> 4) << 3);
}

template<int NG, int MODE>
__global__ __launch_bounds__(256)
void fused_gemm(GArgs g) {
  __shared__ u16 sm[3 * (8192 + 2 * NG * 2048)];
  int cb, rh;
  if (gridDim.x >= 16) map_flat(blockIdx.x, cb, rh);
  else { cb = blockIdx.x >> 1; rh = blockIdx.x & 1; }   // tiny grids (out: 4)
  gemm_body<NG, MODE>(sm, g, cb, rh);
}

// encoder pair: rest<32 -> layer-0 step t, rest>=32 -> layer-1 step t-1
__global__ __launch_bounds__(256)
void gru_pair(GArgs ga, GArgs gb) {
  __shared__ u16 sm[3 * (8192 + 2 * 3 * 2048)];
  int rh = (blockIdx.x >> 3) & 1;
  int rest = (blockIdx.x & 7) | ((blockIdx.x >> 4) << 3);
  if (rest < 32) gemm_body<3, 0>(sm, ga, rest, rh);
  else           gemm_body<3, 0>(sm, gb, rest - 32, rh);
}

// =====================================================================
extern "C" void kernel_launch(void* const* d_in, const int* in_sizes, int n_in,
                              void* d_out, int out_size, void* d_ws, size_t ws_size,
                              hipStream_t stream) {
  const float* X     = (const float*)d_in[0];
  const float* eWih0 = (const float*)d_in[1];
  const float* eWhh0 = (const float*)d_in[2];
  const float* ebih0 = (const float*)d_in[3];
  const float* ebhh0 = (const float*)d_in[4];
  const float* eWih1 = (const float*)d_in[5];
  const float* eWhh1 = (const float*)d_in[6];
  const float* ebih1 = (const float*)d_in[7];
  const float* ebhh1 = (const float*)d_in[8];
  const float* dWih0 = (const float*)d_in[9];
  const float* dWhh0 = (const float*)d_in[10];
  const float* dbih0 = (const float*)d_in[11];
  const float* dbhh0 = (const float*)d_in[12];
  const float* dWih1 = (const float*)d_in[13];
  const float* dWhh1 = (const float*)d_in[14];
  const float* dbih1 = (const float*)d_in[15];
  const float* dbhh1 = (const float*)d_in[16];
  const float* projW = (const float*)d_in[17];
  const float* projb = (const float*)d_in[18];
  const float* outW  = (const float*)d_in[19];
  const float* outb  = (const float*)d_in[20];
  float* outf = (float*)d_out;

  u16* wsp = (u16*)d_ws;
  size_t off = 0;
  auto take = [&](size_t n) { u16* p = wsp + off; off += n; return p; };

  u16* pl_eWih0 = take(32ULL * 1 * 2 * 96 * 64);
  u16* pl_eWhh0 = take(32ULL * 16 * 2 * 96 * 64);
  u16* pl_eWih1 = take(32ULL * 16 * 2 * 96 * 64);
  u16* pl_eWhh1 = take(32ULL * 16 * 2 * 96 * 64);
  u16* pl_dWih0 = take(32ULL * 1 * 2 * 96 * 64);
  u16* pl_dWhh0 = take(32ULL * 16 * 2 * 96 * 64);
  u16* pl_dWih1 = take(32ULL * 16 * 2 * 96 * 64);
  u16* pl_dWhh1 = take(32ULL * 16 * 2 * 96 * 64);
  u16* pl_proj  = take(16ULL * 16 * 2 * 32 * 64);
  u16* pl_out   = take(2ULL * 8 * 2 * 32 * 64);
  u16* pl_x     = take(256ULL * 2 * 128 * 64);
  u16* pl_h0    = take(2ULL * 16 * 2 * 128 * 64);   // 2 slots, stride 262144
  u16* pl_h1    = take(2ULL * 16 * 2 * 128 * 64);
  u16* pl_y     = take(2ULL * 1 * 2 * 128 * 64);    // 2 slots, stride 16384
  u16* pl_p     = take(8ULL * 2 * 128 * 64);
  if (off * 2 > ws_size) return;                    // scratch too small -> loud fail

  hipMemsetAsync(pl_h0, 0, 262144 * 2, stream);     // h0 slot0 = 0
  hipMemsetAsync(pl_h1, 0, 262144 * 2, stream);     // h1 slot0 = 0

  auto pw = [&](const float* W, u16* dst, int colblks, int nc, int rows, int K, int gru) {
    int total = colblks * nc * rows * 8;
    prep_w<<<(total + 255) / 256, 256, 0, stream>>>(W, dst, colblks, nc, rows, K, gru);
  };
  pw(eWih0, pl_eWih0, 32, 1, 96, 64, 1);
  pw(eWhh0, pl_eWhh0, 32, 16, 96, 1024, 1);
  pw(eWih1, pl_eWih1, 32, 16, 96, 1024, 1);
  pw(eWhh1, pl_eWhh1, 32, 16, 96, 1024, 1);
  pw(dWih0, pl_dWih0, 32, 1, 96, 64, 1);
  pw(dWhh0, pl_dWhh0, 32, 16, 96, 1024, 1);
  pw(dWih1, pl_dWih1, 32, 16, 96, 1024, 1);
  pw(dWhh1, pl_dWhh1, 32, 16, 96, 1024, 1);
  pw(projW, pl_proj, 16, 16, 32, 1024, 0);
  pw(outW,  pl_out,  2,  8,  32, 512, 0);
  prep_x<<<1024, 256, 0, stream>>>(X, pl_x);

  // nc0 MUST be threaded through: 1 for x-input (K=64), 16 for h-input (K=1024).
  auto mkL0 = [&](int t, const u16* xs, const float* bih, const float* bhh,
                  const u16* wih, const u16* whh) {
    const u16* h0i = pl_h0 + (size_t)(t & 1) * 262144;
    u16* h0o = pl_h0 + (size_t)((t + 1) & 1) * 262144;
    return GArgs{xs, wih, 1, h0i, whh, 16, bih, bhh, h0i, h0o, nullptr};
  };
  // encoder layer-1, step u: activation = h0 slot((u+1)&1), state = h1 slot(u&1)
  auto mkL1e = [&](int u) {
    const u16* act = pl_h0 + (size_t)((u + 1) & 1) * 262144;
    const u16* h1i = pl_h1 + (size_t)(u & 1) * 262144;
    u16* h1o = pl_h1 + (size_t)((u + 1) & 1) * 262144;
    return GArgs{act, pl_eWih1, 16, h1i, pl_eWhh1, 16, ebih1, ebhh1, h1i, h1o, nullptr};
  };

  // ---------------- encoder: L0[t] || L1[t-1] fused ----------------
  {
    GArgs g0 = mkL0(0, pl_x, ebih0, ebhh0, pl_eWih0, pl_eWhh0);
    fused_gemm<3, 0><<<64, 256, 0, stream>>>(g0);
  }
  for (int t = 1; t < Tdim; ++t) {
    GArgs gA = mkL0(t, pl_x + (size_t)t * 16384, ebih0, ebhh0, pl_eWih0, pl_eWhh0);
    GArgs gB = mkL1e(t - 1);
    gru_pair<<<128, 256, 0, stream>>>(gA, gB);
  }
  {
    GArgs gB = mkL1e(Tdim - 1);
    fused_gemm<3, 0><<<64, 256, 0, stream>>>(gB);
  }

  // ---------------- decoder (serial chain) ----------------
  for (int s = 0; s < OUTLEN; ++s) {
    const u16* xs = (s == 0) ? (pl_x + 255ULL * 16384) : (pl_y + (size_t)((s - 1) & 1) * 16384);
    const u16* h0i = pl_h0 + (size_t)(s & 1) * 262144;
    u16* h0o = pl_h0 + (size_t)((s + 1) & 1) * 262144;
    const u16* h1i = pl_h1 + (size_t)(s & 1) * 262144;
    u16* h1o = pl_h1 + (size_t)((s + 1) & 1) * 262144;

    GArgs g0{xs, pl_dWih0, 1, h0i, pl_dWhh0, 16, dbih0, dbhh0, h0i, h0o, nullptr};
    fused_gemm<3, 0><<<64, 256, 0, stream>>>(g0);
    GArgs g1{h0o, pl_dWih1, 16, h1i, pl_dWhh1, 16, dbih1, dbhh1, h1i, h1o, nullptr};
    fused_gemm<3, 0><<<64, 256, 0, stream>>>(g1);
    GArgs gp{h1o, pl_proj, 16, nullptr, nullptr, 0, projb, nullptr, nullptr, pl_p, nullptr};
    fused_gemm<1, 1><<<32, 256, 0, stream>>>(gp);
    GArgs gy{pl_p, pl_out, 8, nullptr, nullptr, 0, outb, nullptr, nullptr,
             pl_y + (size_t)(s & 1) * 16384, outf + (size_t)s * 64};
    fused_gemm<1, 2><<<4, 256, 0, stream>>>(gy);
  }
}

// Round 12
// 13654.001 us; speedup vs baseline: 1.2062x; 1.2062x over previous
//
#include <hip/hip_runtime.h>

#define Bdim 128
#define Tdim 256
#define Fdim 64
#define Hdim 1024
#define Pdim 512
#define OUTLEN 48

typedef float  f32x4 __attribute__((ext_vector_type(4)));
typedef short  s16x8 __attribute__((ext_vector_type(8)));
typedef unsigned short u16;

__device__ __forceinline__ u16 f2bf(float f) {
  unsigned u = __float_as_uint(f);
  u += 0x7FFFu + ((u >> 16) & 1u);   // RNE
  return (u16)(u >> 16);
}
__device__ __forceinline__ float bf2f(u16 s) { return __uint_as_float(((unsigned)s) << 16); }
// 16B-block XOR swizzle within a 128B row (G4 pattern); returns u16 offset of block
__device__ __forceinline__ int swz8(int row, int blk) { return ((blk ^ (row & 7)) << 3); }

__device__ __forceinline__ f32x4 mfma16(s16x8 a, s16x8 b, f32x4 c) {
  return __builtin_amdgcn_mfma_f32_16x16x32_bf16(a, b, c, 0, 0, 0);
}

// async global->LDS, 16B per lane; lds base must be wave-uniform (HW adds lane*16)
__device__ __forceinline__ void glds16(u16* lds, const u16* g) {
  __builtin_amdgcn_global_load_lds(
      (const __attribute__((address_space(1))) unsigned int*)g,
      (__attribute__((address_space(3))) unsigned int*)lds, 16, 0, 0);
}

// =====================================================================
// prep: fp32 weight [N][K] -> swizzled bf16 hi/lo plane tiles (16-col blocks)
// layout: [colblk][nc][2(hi,lo)][rows][64]  (rows = 48 gru / 16 lin)
// =====================================================================
__global__ __launch_bounds__(256)
void prep_w(const float* __restrict__ W, u16* __restrict__ dst,
            int colblks, int nc, int rows, int K, int gru) {
  int idx = blockIdx.x * 256 + threadIdx.x;
  if (idx >= colblks * nc * rows * 8) return;
  int blk = idx & 7;
  int t = idx >> 3;
  int r = t % rows; t /= rows;
  int c = t % nc;
  int cb = t / nc;
  int srow = gru ? ((r >> 4) * Hdim + cb * 16 + (r & 15)) : (cb * 16 + r);
  const float* src = W + (size_t)srow * K + c * 64 + blk * 8;
  s16x8 vh, vl;
#pragma unroll
  for (int e = 0; e < 8; ++e) {
    float v = src[e];
    u16 h = f2bf(v);
    vh[e] = (short)h;
    vl[e] = (short)f2bf(v - bf2f(h));
  }
  size_t tb = (size_t)(cb * nc + c) * (2 * rows * 64);
  int o = r * 64 + swz8(r, blk);
  *(s16x8*)(dst + tb + o) = vh;
  *(s16x8*)(dst + tb + (size_t)rows * 64 + o) = vl;
}

// X [128][256][64] fp32 -> per-t A-tiles [256][2][128][64]
__global__ __launch_bounds__(256)
void prep_x(const float* __restrict__ X, u16* __restrict__ dst) {
  int idx = blockIdx.x * 256 + threadIdx.x;   // 256*128*8
  int blk = idx & 7;
  int row = (idx >> 3) & 127;
  int t = idx >> 10;
  const float* src = X + (size_t)row * (Tdim * Fdim) + t * 64 + blk * 8;
  s16x8 vh, vl;
#pragma unroll
  for (int e = 0; e < 8; ++e) {
    float v = src[e];
    u16 h = f2bf(v);
    vh[e] = (short)h;
    vl[e] = (short)f2bf(v - bf2f(h));
  }
  size_t tb = (size_t)t * 16384;
  int o = row * 64 + swz8(row, blk);
  *(s16x8*)(dst + tb + o) = vh;
  *(s16x8*)(dst + tb + 8192 + o) = vl;
}

// =====================================================================
// one staged 64-k chunk (3-term hi/lo split), 8-wave form:
// LDS: A hi[128][64] (8192 u16) | A lo (8192) | W hi[NG*16][64] | W lo
// wave wv owns A-rows wv*16..wv*16+15 (full M covered by 8 waves, no mf loop)
// =====================================================================
template<int NG, bool SEG1>
__device__ __forceinline__ void compute_chunk(const u16* __restrict__ A, int lane, int wv,
                                              f32x4* acc) {
  constexpr int WT = NG * 1024;            // u16 per W plane (NG*16 rows x 64)
  const u16* Wp = A + 16384;
#pragma unroll
  for (int kk = 0; kk < 2; ++kk) {
    const int sw = (((kk * 4 + (lane >> 4)) ^ (lane & 7)) << 3);
    s16x8 bh[NG], bl[NG];
#pragma unroll
    for (int g = 0; g < NG; ++g) {
      const u16* wp = Wp + (g * 16 + (lane & 15)) * 64 + sw;
      bh[g] = *(const s16x8*)(wp);
      bl[g] = *(const s16x8*)(wp + WT);
    }
    const u16* ap = A + (wv * 16 + (lane & 15)) * 64 + sw;
    s16x8 ah = *(const s16x8*)(ap);
    s16x8 al = *(const s16x8*)(ap + 8192);
#pragma unroll
    for (int g = 0; g < NG; ++g) {
      const int q = (NG == 3 && g == 2) ? (SEG1 ? 3 : 2) : g;
      acc[q] = mfma16(ah, bh[g], acc[q]);
      acc[q] = mfma16(al, bh[g], acc[q]);
      acc[q] = mfma16(ah, bl[g], acc[q]);
    }
  }
}

// =====================================================================
// argument bundle for one GEMM instance (so two can share a launch)
// =====================================================================
struct GArgs {
  const u16* a0; const u16* w0; int nc0;
  const u16* a1; const u16* w1; int nc1;
  const float* bias0; const float* bias1;
  const u16* hprev; u16* oplanes; float* yout;
};

// =====================================================================
// GEMM body: full-K, full-M per block, 512 threads / 8 waves (2 waves/SIMD
// for TLP latency hiding — r11 showed the chain is latency-bound, not BW).
// 3 LDS buffers, prefetch depth 2, per-wave-class counted vmcnt.
// NG=3 MODE=0: GRU (R,Z,IN,HN; epilogue -> h planes)
// NG=1 MODE=1: proj+relu -> p planes; MODE=2: out -> y planes + f32 d_out
// =====================================================================
template<int NG, int MODE>
__device__ __forceinline__ void gemm_body(u16* __restrict__ sm, const GArgs& g, int cb) {
  constexpr int WT = NG * 1024;            // u16 per W plane tile
  constexpr int BUFU = 16384 + 2 * WT;     // A(hi+lo, 128 rows) + W(hi+lo)
  constexpr int WSEG = (2 * WT) >> 9;      // W segments of 512 u16: 12 gru / 4 lin
  constexpr int NQ = (NG == 3) ? 4 : 1;
  constexpr int D = 2;                     // prefetch depth (3 buffers)

  const int tid = threadIdx.x;
  const int lane = tid & 63;
  const int wv = tid >> 6;                 // 0..7
  const bool hiw = (wv < 4);               // waves 0-3 issue one extra seg
  const int nc0 = g.nc0;
  const int NC = nc0 + g.nc1;

  f32x4 acc[NQ];
#pragma unroll
  for (int q = 0; q < NQ; ++q) acc[q] = f32x4{0.f, 0.f, 0.f, 0.f};

  auto stage = [&](int c, int buf) {
    const u16 *at, *wt;
    if (c < nc0) { at = g.a0 + (size_t)c * 16384; wt = g.w0 + (size_t)(cb * nc0 + c) * (2 * WT); }
    else { int cc = c - nc0; at = g.a1 + (size_t)cc * 16384; wt = g.w1 + (size_t)(cb * g.nc1 + cc) * (2 * WT); }
    u16* sa = sm + buf * BUFU;
    // unified seg loop: segs 0..31 = A (hi+lo contiguous), 32..32+WSEG-1 = W
    for (int i = wv; i < 32 + WSEG; i += 8) {
      if (i < 32) glds16(sa + i * 512, at + i * 512 + lane * 8);
      else        glds16(sa + 16384 + (i - 32) * 512, wt + (size_t)(i - 32) * 512 + lane * 8);
    }
  };
  // per-wave issues per stage: GRU (44 segs): wv<4 -> 6, else 5
  //                            LIN (36 segs): wv<4 -> 5, else 4

  for (int p = 0; p < D && p < NC; ++p) stage(p, p % 3);
  for (int c = 0; c < NC; ++c) {
    if (c + D < NC) stage(c + D, (c + D) % 3);
    const int rem = NC - 1 - c;
    const int gg = rem < D ? rem : D;                // stage-groups newer than c
    if constexpr (NG == 3) {
      if (hiw) {
        switch (gg) {
          case 2:  asm volatile("s_waitcnt vmcnt(12)" ::: "memory"); break;
          case 1:  asm volatile("s_waitcnt vmcnt(6)"  ::: "memory"); break;
          default: asm volatile("s_waitcnt vmcnt(0)"  ::: "memory");
        }
      } else {
        switch (gg) {
          case 2:  asm volatile("s_waitcnt vmcnt(10)" ::: "memory"); break;
          case 1:  asm volatile("s_waitcnt vmcnt(5)"  ::: "memory"); break;
          default: asm volatile("s_waitcnt vmcnt(0)"  ::: "memory");
        }
      }
    } else {
      if (hiw) {
        switch (gg) {
          case 2:  asm volatile("s_waitcnt vmcnt(10)" ::: "memory"); break;
          case 1:  asm volatile("s_waitcnt vmcnt(5)"  ::: "memory"); break;
          default: asm volatile("s_waitcnt vmcnt(0)"  ::: "memory");
        }
      } else {
        switch (gg) {
          case 2:  asm volatile("s_waitcnt vmcnt(8)" ::: "memory"); break;
          case 1:  asm volatile("s_waitcnt vmcnt(4)" ::: "memory"); break;
          default: asm volatile("s_waitcnt vmcnt(0)" ::: "memory");
        }
      }
    }
    __builtin_amdgcn_s_barrier();
    asm volatile("" ::: "memory");
    const u16* A = sm + (c % 3) * BUFU;
    if (c < nc0) compute_chunk<NG, false>(A, lane, wv, acc);
    else         compute_chunk<NG, true>(A, lane, wv, acc);
    asm volatile("s_waitcnt lgkmcnt(0)" ::: "memory");
    __builtin_amdgcn_s_barrier();
    asm volatile("" ::: "memory");
  }

  // ---- epilogue (C layout: col=lane&15, row=wv*16+(lane>>4)*4+e) ----
  const int j = cb * 16 + (lane & 15);
  const int ch = j >> 6, k6 = j & 63;
  const int rowbase = wv * 16 + ((lane >> 4) << 2);

  if constexpr (MODE == 0) {
    const float b_r = g.bias0[j] + g.bias1[j];
    const float b_z = g.bias0[Hdim + j] + g.bias1[Hdim + j];
    const float b_in = g.bias0[2 * Hdim + j];
    const float b_hn = g.bias1[2 * Hdim + j];
#pragma unroll
    for (int e = 0; e < 4; ++e) {
      const int r = rowbase + e;
      const int o = ch * 16384 + r * 64 + swz8(r, k6 >> 3) + (k6 & 7);
      const float hp = bf2f(g.hprev[o]) + bf2f(g.hprev[o + 8192]);
      const float rr = 1.f / (1.f + expf(-(acc[0][e] + b_r)));
      const float zz = 1.f / (1.f + expf(-(acc[1][e] + b_z)));
      const float nn = tanhf(acc[2][e] + b_in + rr * (acc[3][e] + b_hn));
      const float h = (1.f - zz) * nn + zz * hp;
      const u16 hh = f2bf(h);
      g.oplanes[o] = hh;
      g.oplanes[o + 8192] = f2bf(h - bf2f(hh));
    }
  } else {
    const float bb = g.bias0[j];
#pragma unroll
    for (int e = 0; e < 4; ++e) {
      const int r = rowbase + e;
      float v = acc[0][e] + bb;
      if constexpr (MODE == 1) v = fmaxf(v, 0.f);
      const int o = ch * 16384 + r * 64 + swz8(r, k6 >> 3) + (k6 & 7);
      const u16 hh = f2bf(v);
      g.oplanes[o] = hh;
      g.oplanes[o + 8192] = f2bf(v - bf2f(hh));
      if constexpr (MODE == 2) g.yout[(size_t)r * (OUTLEN * Fdim) + j] = v;
    }
  }
}

template<int NG, int MODE>
__global__ __launch_bounds__(512)
void fused_gemm(GArgs g) {
  __shared__ u16 sm[3 * (16384 + 2 * NG * 1024)];
  gemm_body<NG, MODE>(sm, g, blockIdx.x);
}

// encoder pair: blocks 0-63 run layer-0 step t, 64-127 run layer-1 step t-1
__global__ __launch_bounds__(512)
void gru_pair(GArgs ga, GArgs gb) {
  __shared__ u16 sm[3 * (16384 + 2 * 3 * 1024)];
  if (blockIdx.x < 64) gemm_body<3, 0>(sm, ga, blockIdx.x);
  else                 gemm_body<3, 0>(sm, gb, blockIdx.x - 64);
}

// =====================================================================
extern "C" void kernel_launch(void* const* d_in, const int* in_sizes, int n_in,
                              void* d_out, int out_size, void* d_ws, size_t ws_size,
                              hipStream_t stream) {
  const float* X     = (const float*)d_in[0];
  const float* eWih0 = (const float*)d_in[1];
  const float* eWhh0 = (const float*)d_in[2];
  const float* ebih0 = (const float*)d_in[3];
  const float* ebhh0 = (const float*)d_in[4];
  const float* eWih1 = (const float*)d_in[5];
  const float* eWhh1 = (const float*)d_in[6];
  const float* ebih1 = (const float*)d_in[7];
  const float* ebhh1 = (const float*)d_in[8];
  const float* dWih0 = (const float*)d_in[9];
  const float* dWhh0 = (const float*)d_in[10];
  const float* dbih0 = (const float*)d_in[11];
  const float* dbhh0 = (const float*)d_in[12];
  const float* dWih1 = (const float*)d_in[13];
  const float* dWhh1 = (const float*)d_in[14];
  const float* dbih1 = (const float*)d_in[15];
  const float* dbhh1 = (const float*)d_in[16];
  const float* projW = (const float*)d_in[17];
  const float* projb = (const float*)d_in[18];
  const float* outW  = (const float*)d_in[19];
  const float* outb  = (const float*)d_in[20];
  float* outf = (float*)d_out;

  u16* wsp = (u16*)d_ws;
  size_t off = 0;
  auto take = [&](size_t n) { u16* p = wsp + off; off += n; return p; };

  u16* pl_eWih0 = take(64ULL * 1 * 2 * 48 * 64);
  u16* pl_eWhh0 = take(64ULL * 16 * 2 * 48 * 64);
  u16* pl_eWih1 = take(64ULL * 16 * 2 * 48 * 64);
  u16* pl_eWhh1 = take(64ULL * 16 * 2 * 48 * 64);
  u16* pl_dWih0 = take(64ULL * 1 * 2 * 48 * 64);
  u16* pl_dWhh0 = take(64ULL * 16 * 2 * 48 * 64);
  u16* pl_dWih1 = take(64ULL * 16 * 2 * 48 * 64);
  u16* pl_dWhh1 = take(64ULL * 16 * 2 * 48 * 64);
  u16* pl_proj  = take(32ULL * 16 * 2 * 16 * 64);
  u16* pl_out   = take(4ULL * 8 * 2 * 16 * 64);
  u16* pl_x     = take(256ULL * 2 * 128 * 64);
  u16* pl_h0    = take(2ULL * 16 * 2 * 128 * 64);   // 2 slots, stride 262144
  u16* pl_h1    = take(2ULL * 16 * 2 * 128 * 64);
  u16* pl_y     = take(2ULL * 1 * 2 * 128 * 64);    // 2 slots, stride 16384
  u16* pl_p     = take(8ULL * 2 * 128 * 64);
  if (off * 2 > ws_size) return;                    // scratch too small -> loud fail

  hipMemsetAsync(pl_h0, 0, 262144 * 2, stream);     // h0 slot0 = 0
  hipMemsetAsync(pl_h1, 0, 262144 * 2, stream);     // h1 slot0 = 0

  auto pw = [&](const float* W, u16* dst, int colblks, int nc, int rows, int K, int gru) {
    int total = colblks * nc * rows * 8;
    prep_w<<<(total + 255) / 256, 256, 0, stream>>>(W, dst, colblks, nc, rows, K, gru);
  };
  pw(eWih0, pl_eWih0, 64, 1, 48, 64, 1);
  pw(eWhh0, pl_eWhh0, 64, 16, 48, 1024, 1);
  pw(eWih1, pl_eWih1, 64, 16, 48, 1024, 1);
  pw(eWhh1, pl_eWhh1, 64, 16, 48, 1024, 1);
  pw(dWih0, pl_dWih0, 64, 1, 48, 64, 1);
  pw(dWhh0, pl_dWhh0, 64, 16, 48, 1024, 1);
  pw(dWih1, pl_dWih1, 64, 16, 48, 1024, 1);
  pw(dWhh1, pl_dWhh1, 64, 16, 48, 1024, 1);
  pw(projW, pl_proj, 32, 16, 16, 1024, 0);
  pw(outW,  pl_out,  4,  8,  16, 512, 0);
  prep_x<<<1024, 256, 0, stream>>>(X, pl_x);

  // nc0 MUST be threaded through: 1 for x-input (K=64), 16 for h-input (K=1024).
  auto mkL0 = [&](int t, const u16* xs, const float* bih, const float* bhh,
                  const u16* wih, const u16* whh) {
    const u16* h0i = pl_h0 + (size_t)(t & 1) * 262144;
    u16* h0o = pl_h0 + (size_t)((t + 1) & 1) * 262144;
    return GArgs{xs, wih, 1, h0i, whh, 16, bih, bhh, h0i, h0o, nullptr};
  };
  // encoder layer-1, step u: activation = h0 slot((u+1)&1), state = h1 slot(u&1)
  auto mkL1e = [&](int u) {
    const u16* act = pl_h0 + (size_t)((u + 1) & 1) * 262144;
    const u16* h1i = pl_h1 + (size_t)(u & 1) * 262144;
    u16* h1o = pl_h1 + (size_t)((u + 1) & 1) * 262144;
    return GArgs{act, pl_eWih1, 16, h1i, pl_eWhh1, 16, ebih1, ebhh1, h1i, h1o, nullptr};
  };

  // ---------------- encoder: L0[t] || L1[t-1] fused ----------------
  {
    GArgs g0 = mkL0(0, pl_x, ebih0, ebhh0, pl_eWih0, pl_eWhh0);
    fused_gemm<3, 0><<<64, 512, 0, stream>>>(g0);
  }
  for (int t = 1; t < Tdim; ++t) {
    GArgs gA = mkL0(t, pl_x + (size_t)t * 16384, ebih0, ebhh0, pl_eWih0, pl_eWhh0);
    GArgs gB = mkL1e(t - 1);
    gru_pair<<<128, 512, 0, stream>>>(gA, gB);
  }
  {
    GArgs gB = mkL1e(Tdim - 1);
    fused_gemm<3, 0><<<64, 512, 0, stream>>>(gB);
  }

  // ---------------- decoder (serial chain) ----------------
  for (int s = 0; s < OUTLEN; ++s) {
    const u16* xs = (s == 0) ? (pl_x + 255ULL * 16384) : (pl_y + (size_t)((s - 1) & 1) * 16384);
    const u16* h0i = pl_h0 + (size_t)(s & 1) * 262144;
    u16* h0o = pl_h0 + (size_t)((s + 1) & 1) * 262144;
    const u16* h1i = pl_h1 + (size_t)(s & 1) * 262144;
    u16* h1o = pl_h1 + (size_t)((s + 1) & 1) * 262144;

    GArgs g0{xs, pl_dWih0, 1, h0i, pl_dWhh0, 16, dbih0, dbhh0, h0i, h0o, nullptr};
    fused_gemm<3, 0><<<64, 512, 0, stream>>>(g0);
    GArgs g1{h0o, pl_dWih1, 16, h1i, pl_dWhh1, 16, dbih1, dbhh1, h1i, h1o, nullptr};
    fused_gemm<3, 0><<<64, 512, 0, stream>>>(g1);
    GArgs gp{h1o, pl_proj, 16, nullptr, nullptr, 0, projb, nullptr, nullptr, pl_p, nullptr};
    fused_gemm<1, 1><<<32, 512, 0, stream>>>(gp);
    GArgs gy{pl_p, pl_out, 8, nullptr, nullptr, 0, outb, nullptr, nullptr,
             pl_y + (size_t)(s & 1) * 16384, outf + (size_t)s * 64};
    fused_gemm<1, 2><<<4, 512, 0, stream>>>(gy);
  }
}

// Round 13
// 11224.557 us; speedup vs baseline: 1.4673x; 1.2164x over previous
//
#include <hip/hip_runtime.h>

#define Bdim 128
#define Tdim 256
#define Fdim 64
#define Hdim 1024
#define Pdim 512
#define OUTLEN 48

typedef float  f32x4 __attribute__((ext_vector_type(4)));
typedef short  s16x8 __attribute__((ext_vector_type(8)));
typedef unsigned short u16;

__device__ __forceinline__ u16 f2bf(float f) {
  unsigned u = __float_as_uint(f);
  u += 0x7FFFu + ((u >> 16) & 1u);   // RNE
  return (u16)(u >> 16);
}
__device__ __forceinline__ float bf2f(u16 s) { return __uint_as_float(((unsigned)s) << 16); }
// 16B-block XOR swizzle within a 128B row (G4 pattern); returns u16 offset of block
__device__ __forceinline__ int swz8(int row, int blk) { return ((blk ^ (row & 7)) << 3); }

__device__ __forceinline__ f32x4 mfma16(s16x8 a, s16x8 b, f32x4 c) {
  return __builtin_amdgcn_mfma_f32_16x16x32_bf16(a, b, c, 0, 0, 0);
}

// async global->LDS, 16B per lane; lds base must be wave-uniform (HW adds lane*16)
__device__ __forceinline__ void glds16(u16* lds, const u16* g) {
  __builtin_amdgcn_global_load_lds(
      (const __attribute__((address_space(1))) unsigned int*)g,
      (__attribute__((address_space(3))) unsigned int*)lds, 16, 0, 0);
}

// =====================================================================
// prep: fp32 weight [N][K] -> swizzled bf16 hi/lo plane tiles (16-col blocks)
// layout: [colblk][nc][2(hi,lo)][rows][64]  (rows = 48 gru / 16 lin)
// =====================================================================
__global__ __launch_bounds__(256)
void prep_w(const float* __restrict__ W, u16* __restrict__ dst,
            int colblks, int nc, int rows, int K, int gru) {
  int idx = blockIdx.x * 256 + threadIdx.x;
  if (idx >= colblks * nc * rows * 8) return;
  int blk = idx & 7;
  int t = idx >> 3;
  int r = t % rows; t /= rows;
  int c = t % nc;
  int cb = t / nc;
  int srow = gru ? ((r >> 4) * Hdim + cb * 16 + (r & 15)) : (cb * 16 + r);
  const float* src = W + (size_t)srow * K + c * 64 + blk * 8;
  s16x8 vh, vl;
#pragma unroll
  for (int e = 0; e < 8; ++e) {
    float v = src[e];
    u16 h = f2bf(v);
    vh[e] = (short)h;
    vl[e] = (short)f2bf(v - bf2f(h));
  }
  size_t tb = (size_t)(cb * nc + c) * (2 * rows * 64);
  int o = r * 64 + swz8(r, blk);
  *(s16x8*)(dst + tb + o) = vh;
  *(s16x8*)(dst + tb + (size_t)rows * 64 + o) = vl;
}

// X [128][256][64] fp32 -> per-t A-tiles [256][2][128][64]
__global__ __launch_bounds__(256)
void prep_x(const float* __restrict__ X, u16* __restrict__ dst) {
  int idx = blockIdx.x * 256 + threadIdx.x;   // 256*128*8
  int blk = idx & 7;
  int row = (idx >> 3) & 127;
  int t = idx >> 10;
  const float* src = X + (size_t)row * (Tdim * Fdim) + t * 64 + blk * 8;
  s16x8 vh, vl;
#pragma unroll
  for (int e = 0; e < 8; ++e) {
    float v = src[e];
    u16 h = f2bf(v);
    vh[e] = (short)h;
    vl[e] = (short)f2bf(v - bf2f(h));
  }
  size_t tb = (size_t)t * 16384;
  int o = row * 64 + swz8(row, blk);
  *(s16x8*)(dst + tb + o) = vh;
  *(s16x8*)(dst + tb + 8192 + o) = vl;
}

// =====================================================================
// one staged 64-k chunk (3-term hi/lo split), M-split form (64 rows/block):
// LDS buf: A hi[64][64] (4096 u16) | A lo (4096) | W hi[NG*16][64] | W lo
// each of 4 waves owns 16 A-rows -> one MFMA row-tile
// =====================================================================
template<int NG, bool SEG1>
__device__ __forceinline__ void compute_chunk(const u16* __restrict__ A, int lane, int wv,
                                              f32x4* acc) {
  constexpr int WT = NG * 1024;
  const u16* Wp = A + 8192;
#pragma unroll
  for (int kk = 0; kk < 2; ++kk) {
    const int sw = (((kk * 4 + (lane >> 4)) ^ (lane & 7)) << 3);
    s16x8 bh[NG], bl[NG];
#pragma unroll
    for (int g = 0; g < NG; ++g) {
      const u16* wp = Wp + (g * 16 + (lane & 15)) * 64 + sw;
      bh[g] = *(const s16x8*)(wp);
      bl[g] = *(const s16x8*)(wp + WT);
    }
    const u16* ap = A + (wv * 16 + (lane & 15)) * 64 + sw;
    s16x8 ah = *(const s16x8*)(ap);
    s16x8 al = *(const s16x8*)(ap + 4096);
#pragma unroll
    for (int g = 0; g < NG; ++g) {
      const int q = (NG == 3 && g == 2) ? (SEG1 ? 3 : 2) : g;
      acc[q] = mfma16(ah, bh[g], acc[q]);
      acc[q] = mfma16(al, bh[g], acc[q]);
      acc[q] = mfma16(ah, bl[g], acc[q]);
    }
  }
}

// =====================================================================
// argument bundle for one GEMM instance (so two can share a launch)
// =====================================================================
struct GArgs {
  const u16* a0; const u16* w0; int nc0;
  const u16* a1; const u16* w1; int nc1;
  const float* bias0; const float* bias1;
  const u16* hprev; u16* oplanes; float* yout;
};

// =====================================================================
// GEMM body: full-K per block, M-split (rh), 4 LDS buffers, PAIRED PHASES:
// per phase {barrier; stage next pair; vmcnt(counted); compute 2 chunks;
// lgkmcnt(0)} -> 1 barrier + 1 wait per 2 chunks (r9 had 4+2).
// NG=3 MODE=0: GRU (R,Z,IN,HN; epilogue -> h planes)
// NG=1 MODE=1: proj+relu -> p planes; MODE=2: out -> y planes + f32 d_out
// =====================================================================
template<int NG, int MODE>
__device__ __forceinline__ void gemm_body(u16* __restrict__ sm, const GArgs& g,
                                          int cb, int rh) {
  constexpr int WT = NG * 1024;            // u16 per W plane tile
  constexpr int BUFU = 8192 + 2 * WT;      // A(hi+lo, 64 rows) + W(hi+lo)
  constexpr int NQ = (NG == 3) ? 4 : 1;

  const int tid = threadIdx.x;
  const int lane = tid & 63;
  const int wv = tid >> 6;
  const int nc0 = g.nc0;
  const int NC = nc0 + g.nc1;

  f32x4 acc[NQ];
#pragma unroll
  for (int q = 0; q < NQ; ++q) acc[q] = f32x4{0.f, 0.f, 0.f, 0.f};

  auto stage = [&](int c, int buf) {
    const u16 *at, *wt;
    if (c < nc0) { at = g.a0 + (size_t)c * 16384; wt = g.w0 + (size_t)(cb * nc0 + c) * (2 * WT); }
    else { int cc = c - nc0; at = g.a1 + (size_t)cc * 16384; wt = g.w1 + (size_t)(cb * g.nc1 + cc) * (2 * WT); }
    u16* sa = sm + buf * BUFU;
    for (int i = wv; i < 16; i += 4)                 // A half: 16 KB -> 4 issues/wave
      glds16(sa + i * 512, at + ((i & 8) ? 8192 : 0) + rh * 4096 + (i & 7) * 512 + lane * 8);
    u16* swl = sa + 8192;
    for (int i = wv; i < (WT >> 8); i += 4)          // W: GRU 3/wave, LIN 1/wave
      glds16(swl + i * 512, wt + i * 512 + lane * 8);
  };
  // per-wave issues per chunk-stage: 4 + (WT>>8)/4 -> 7 (GRU) / 5 (linear)

  stage(0, 0);
  if (NC > 1) stage(1, 1);
  for (int c = 0; c < NC; c += 2) {
    __builtin_amdgcn_s_barrier();                    // prev pair's reads done
    asm volatile("" ::: "memory");
    int nn = 0;                                      // chunks staged for next pair
    if (c + 2 < NC) { stage(c + 2, (c + 2) & 3); ++nn; }
    if (c + 3 < NC) { stage(c + 3, (c + 3) & 3); ++nn; }
    if constexpr (NG == 3) {
      if (nn == 2)      asm volatile("s_waitcnt vmcnt(14)" ::: "memory");
      else if (nn == 1) asm volatile("s_waitcnt vmcnt(7)"  ::: "memory");
      else              asm volatile("s_waitcnt vmcnt(0)"  ::: "memory");
    } else {
      if (nn == 2)      asm volatile("s_waitcnt vmcnt(10)" ::: "memory");
      else if (nn == 1) asm volatile("s_waitcnt vmcnt(5)"  ::: "memory");
      else              asm volatile("s_waitcnt vmcnt(0)"  ::: "memory");
    }
    asm volatile("" ::: "memory");
    const u16* A0 = sm + (c & 3) * BUFU;
    if (c < nc0) compute_chunk<NG, false>(A0, lane, wv, acc);
    else         compute_chunk<NG, true>(A0, lane, wv, acc);
    if (c + 1 < NC) {
      const u16* A1 = sm + ((c + 1) & 3) * BUFU;
      if (c + 1 < nc0) compute_chunk<NG, false>(A1, lane, wv, acc);
      else             compute_chunk<NG, true>(A1, lane, wv, acc);
    }
    asm volatile("s_waitcnt lgkmcnt(0)" ::: "memory");
  }

  // ---- epilogue (C layout: col=lane&15, row(local)=wv*16+(lane>>4)*4+e) ----
  const int j = cb * 16 + (lane & 15);
  const int ch = j >> 6, k6 = j & 63;
  const int rowbase = rh * 64 + wv * 16 + ((lane >> 4) << 2);

  if constexpr (MODE == 0) {
    const float b_r = g.bias0[j] + g.bias1[j];
    const float b_z = g.bias0[Hdim + j] + g.bias1[Hdim + j];
    const float b_in = g.bias0[2 * Hdim + j];
    const float b_hn = g.bias1[2 * Hdim + j];
#pragma unroll
    for (int e = 0; e < 4; ++e) {
      const int r = rowbase + e;
      const int o = ch * 16384 + r * 64 + swz8(r, k6 >> 3) + (k6 & 7);
      const float hp = bf2f(g.hprev[o]) + bf2f(g.hprev[o + 8192]);
      const float rr = 1.f / (1.f + expf(-(acc[0][e] + b_r)));
      const float zz = 1.f / (1.f + expf(-(acc[1][e] + b_z)));
      const float nn = tanhf(acc[2][e] + b_in + rr * (acc[3][e] + b_hn));
      const float h = (1.f - zz) * nn + zz * hp;
      const u16 hh = f2bf(h);
      g.oplanes[o] = hh;
      g.oplanes[o + 8192] = f2bf(h - bf2f(hh));
    }
  } else {
    const float bb = g.bias0[j];
#pragma unroll
    for (int e = 0; e < 4; ++e) {
      const int r = rowbase + e;
      float v = acc[0][e] + bb;
      if constexpr (MODE == 1) v = fmaxf(v, 0.f);
      const int o = ch * 16384 + r * 64 + swz8(r, k6 >> 3) + (k6 & 7);
      const u16 hh = f2bf(v);
      g.oplanes[o] = hh;
      g.oplanes[o + 8192] = f2bf(v - bf2f(hh));
      if constexpr (MODE == 2) g.yout[(size_t)r * (OUTLEN * Fdim) + j] = v;
    }
  }
}

template<int NG, int MODE>
__global__ __launch_bounds__(256)
void fused_gemm(GArgs g) {
  __shared__ u16 sm[4 * (8192 + 2 * NG * 1024)];
  gemm_body<NG, MODE>(sm, g, blockIdx.x, blockIdx.y);
}

// encoder pair: x<64 -> layer-0 step t, x>=64 -> layer-1 step t-1; y = row-half
__global__ __launch_bounds__(256)
void gru_pair(GArgs ga, GArgs gb) {
  __shared__ u16 sm[4 * (8192 + 2 * 3 * 1024)];
  if (blockIdx.x < 64) gemm_body<3, 0>(sm, ga, blockIdx.x, blockIdx.y);
  else                 gemm_body<3, 0>(sm, gb, blockIdx.x - 64, blockIdx.y);
}

// =====================================================================
extern "C" void kernel_launch(void* const* d_in, const int* in_sizes, int n_in,
                              void* d_out, int out_size, void* d_ws, size_t ws_size,
                              hipStream_t stream) {
  const float* X     = (const float*)d_in[0];
  const float* eWih0 = (const float*)d_in[1];
  const float* eWhh0 = (const float*)d_in[2];
  const float* ebih0 = (const float*)d_in[3];
  const float* ebhh0 = (const float*)d_in[4];
  const float* eWih1 = (const float*)d_in[5];
  const float* eWhh1 = (const float*)d_in[6];
  const float* ebih1 = (const float*)d_in[7];
  const float* ebhh1 = (const float*)d_in[8];
  const float* dWih0 = (const float*)d_in[9];
  const float* dWhh0 = (const float*)d_in[10];
  const float* dbih0 = (const float*)d_in[11];
  const float* dbhh0 = (const float*)d_in[12];
  const float* dWih1 = (const float*)d_in[13];
  const float* dWhh1 = (const float*)d_in[14];
  const float* dbih1 = (const float*)d_in[15];
  const float* dbhh1 = (const float*)d_in[16];
  const float* projW = (const float*)d_in[17];
  const float* projb = (const float*)d_in[18];
  const float* outW  = (const float*)d_in[19];
  const float* outb  = (const float*)d_in[20];
  float* outf = (float*)d_out;

  u16* wsp = (u16*)d_ws;
  size_t off = 0;
  auto take = [&](size_t n) { u16* p = wsp + off; off += n; return p; };

  u16* pl_eWih0 = take(64ULL * 1 * 2 * 48 * 64);
  u16* pl_eWhh0 = take(64ULL * 16 * 2 * 48 * 64);
  u16* pl_eWih1 = take(64ULL * 16 * 2 * 48 * 64);
  u16* pl_eWhh1 = take(64ULL * 16 * 2 * 48 * 64);
  u16* pl_dWih0 = take(64ULL * 1 * 2 * 48 * 64);
  u16* pl_dWhh0 = take(64ULL * 16 * 2 * 48 * 64);
  u16* pl_dWih1 = take(64ULL * 16 * 2 * 48 * 64);
  u16* pl_dWhh1 = take(64ULL * 16 * 2 * 48 * 64);
  u16* pl_proj  = take(32ULL * 16 * 2 * 16 * 64);
  u16* pl_out   = take(4ULL * 8 * 2 * 16 * 64);
  u16* pl_x     = take(256ULL * 2 * 128 * 64);
  u16* pl_h0    = take(2ULL * 16 * 2 * 128 * 64);   // 2 slots, stride 262144
  u16* pl_h1    = take(2ULL * 16 * 2 * 128 * 64);
  u16* pl_y     = take(2ULL * 1 * 2 * 128 * 64);    // 2 slots, stride 16384
  u16* pl_p     = take(8ULL * 2 * 128 * 64);
  if (off * 2 > ws_size) return;                    // scratch too small -> loud fail

  hipMemsetAsync(pl_h0, 0, 262144 * 2, stream);     // h0 slot0 = 0
  hipMemsetAsync(pl_h1, 0, 262144 * 2, stream);     // h1 slot0 = 0

  auto pw = [&](const float* W, u16* dst, int colblks, int nc, int rows, int K, int gru) {
    int total = colblks * nc * rows * 8;
    prep_w<<<(total + 255) / 256, 256, 0, stream>>>(W, dst, colblks, nc, rows, K, gru);
  };
  pw(eWih0, pl_eWih0, 64, 1, 48, 64, 1);
  pw(eWhh0, pl_eWhh0, 64, 16, 48, 1024, 1);
  pw(eWih1, pl_eWih1, 64, 16, 48, 1024, 1);
  pw(eWhh1, pl_eWhh1, 64, 16, 48, 1024, 1);
  pw(dWih0, pl_dWih0, 64, 1, 48, 64, 1);
  pw(dWhh0, pl_dWhh0, 64, 16, 48, 1024, 1);
  pw(dWih1, pl_dWih1, 64, 16, 48, 1024, 1);
  pw(dWhh1, pl_dWhh1, 64, 16, 48, 1024, 1);
  pw(projW, pl_proj, 32, 16, 16, 1024, 0);
  pw(outW,  pl_out,  4,  8,  16, 512, 0);
  prep_x<<<1024, 256, 0, stream>>>(X, pl_x);

  // nc0 MUST be threaded through: 1 for x-input (K=64), 16 for h-input (K=1024).
  auto mkL0 = [&](int t, const u16* xs, const float* bih, const float* bhh,
                  const u16* wih, const u16* whh) {
    const u16* h0i = pl_h0 + (size_t)(t & 1) * 262144;
    u16* h0o = pl_h0 + (size_t)((t + 1) & 1) * 262144;
    return GArgs{xs, wih, 1, h0i, whh, 16, bih, bhh, h0i, h0o, nullptr};
  };
  // encoder layer-1, step u: activation = h0 slot((u+1)&1), state = h1 slot(u&1)
  auto mkL1e = [&](int u) {
    const u16* act = pl_h0 + (size_t)((u + 1) & 1) * 262144;
    const u16* h1i = pl_h1 + (size_t)(u & 1) * 262144;
    u16* h1o = pl_h1 + (size_t)((u + 1) & 1) * 262144;
    return GArgs{act, pl_eWih1, 16, h1i, pl_eWhh1, 16, ebih1, ebhh1, h1i, h1o, nullptr};
  };

  // ---------------- encoder: L0[t] || L1[t-1] fused ----------------
  {
    GArgs g0 = mkL0(0, pl_x, ebih0, ebhh0, pl_eWih0, pl_eWhh0);
    fused_gemm<3, 0><<<dim3(64, 2), 256, 0, stream>>>(g0);
  }
  for (int t = 1; t < Tdim; ++t) {
    GArgs gA = mkL0(t, pl_x + (size_t)t * 16384, ebih0, ebhh0, pl_eWih0, pl_eWhh0);
    GArgs gB = mkL1e(t - 1);
    gru_pair<<<dim3(128, 2), 256, 0, stream>>>(gA, gB);
  }
  {
    GArgs gB = mkL1e(Tdim - 1);
    fused_gemm<3, 0><<<dim3(64, 2), 256, 0, stream>>>(gB);
  }

  // ---------------- decoder (serial chain) ----------------
  for (int s = 0; s < OUTLEN; ++s) {
    const u16* xs = (s == 0) ? (pl_x + 255ULL * 16384) : (pl_y + (size_t)((s - 1) & 1) * 16384);
    const u16* h0i = pl_h0 + (size_t)(s & 1) * 262144;
    u16* h0o = pl_h0 + (size_t)((s + 1) & 1) * 262144;
    const u16* h1i = pl_h1 + (size_t)(s & 1) * 262144;
    u16* h1o = pl_h1 + (size_t)((s + 1) & 1) * 262144;

    GArgs g0{xs, pl_dWih0, 1, h0i, pl_dWhh0, 16, dbih0, dbhh0, h0i, h0o, nullptr};
    fused_gemm<3, 0><<<dim3(64, 2), 256, 0, stream>>>(g0);
    GArgs g1{h0o, pl_dWih1, 16, h1i, pl_dWhh1, 16, dbih1, dbhh1, h1i, h1o, nullptr};
    fused_gemm<3, 0><<<dim3(64, 2), 256, 0, stream>>>(g1);
    GArgs gp{h1o, pl_proj, 16, nullptr, nullptr, 0, projb, nullptr, nullptr, pl_p, nullptr};
    fused_gemm<1, 1><<<dim3(32, 2), 256, 0, stream>>>(gp);
    GArgs gy{pl_p, pl_out, 8, nullptr, nullptr, 0, outb, nullptr, nullptr,
             pl_y + (size_t)(s & 1) * 16384, outf + (size_t)s * 64};
    fused_gemm<1, 2><<<dim3(4, 2), 256, 0, stream>>>(gy);
  }
}